// Round 7
// baseline (389.703 us; speedup 1.0000x reference)
//
#include <hip/hip_runtime.h>

#define NN   100000
#define NE   1600000
#define DIN  128
#define DH   64
#define DOUT 128
#define NG   512

#define NB   391     // dst buckets of 256 nodes: ceil(NN/256)
#define EPB  6250    // edges per partition block: NE/256
#define MSZ  (NB*256) // 100,096 — scan length

// ---------- radix pass A1: per-(block,bucket) histogram ----------
__global__ __launch_bounds__(256) void histA_kernel(
    const int* __restrict__ dst, int* __restrict__ cnt) {
  __shared__ int h[NB];
  for (int i = threadIdx.x; i < NB; i += 256) h[i] = 0;
  __syncthreads();
  int start = blockIdx.x * EPB, end = start + EPB;
  for (int e = start + threadIdx.x; e < end; e += 256)
    atomicAdd(&h[dst[e] >> 8], 1);
  __syncthreads();
  for (int b = threadIdx.x; b < NB; b += 256)
    cnt[b * 256 + blockIdx.x] = h[b];   // bucket-major layout
}

// ---------- scan pass 1: per-block sums ----------
__global__ __launch_bounds__(256) void reduce_kernel(
    const int* __restrict__ cnt, int* __restrict__ partials) {
  __shared__ int s[256];
  int i = blockIdx.x * 256 + threadIdx.x;
  s[threadIdx.x] = cnt[i];
  __syncthreads();
  for (int off = 128; off > 0; off >>= 1) {
    if (threadIdx.x < off) s[threadIdx.x] += s[threadIdx.x + off];
    __syncthreads();
  }
  if (threadIdx.x == 0) partials[blockIdx.x] = s[0];
}

// ---------- scan pass 2: exclusive scan of NB partials (1 block) ----------
__global__ __launch_bounds__(256) void scanpart_kernel(int* __restrict__ partials) {
  __shared__ int s[NB];
  for (int i = threadIdx.x; i < NB; i += 256) s[i] = partials[i];
  __syncthreads();
  if (threadIdx.x == 0) {
    int run = 0;
    for (int i = 0; i < NB; ++i) { int v = s[i]; s[i] = run; run += v; }
  }
  __syncthreads();
  for (int i = threadIdx.x; i < NB; i += 256) partials[i] = s[i];
}

// ---------- scan pass 3: per-block exclusive scan + offset ----------
__global__ __launch_bounds__(256) void scanfinal_kernel(
    const int* __restrict__ cnt, const int* __restrict__ partials,
    int* __restrict__ scanned) {
  __shared__ int s[256];
  int t = threadIdx.x;
  int i = blockIdx.x * 256 + t;
  int c = cnt[i];
  s[t] = c;
  __syncthreads();
  for (int off = 1; off < 256; off <<= 1) {
    int v = (t >= off) ? s[t - off] : 0;
    __syncthreads();
    s[t] += v;
    __syncthreads();
  }
  scanned[i] = s[t] - c + partials[blockIdx.x];
}

// ---------- radix pass A2: partition packed edges into buckets ----------
__global__ __launch_bounds__(256) void partA_kernel(
    const int* __restrict__ src, const int* __restrict__ dst,
    const int* __restrict__ scanned, int* __restrict__ part) {
  __shared__ int cur[NB];
  for (int i = threadIdx.x; i < NB; i += 256)
    cur[i] = scanned[i * 256 + blockIdx.x];
  __syncthreads();
  int start = blockIdx.x * EPB, end = start + EPB;
  for (int e = start + threadIdx.x; e < end; e += 256) {
    int d = dst[e], s = src[e];
    int pos = atomicAdd(&cur[d >> 8], 1);
    part[pos] = ((d & 255) << 17) | s;
  }
}

// ---------- radix pass B: per-bucket CSR (row_start + eidx) ----------
__global__ __launch_bounds__(256) void bucket_csr_kernel(
    const int* __restrict__ part, const int* __restrict__ scanned,
    int* __restrict__ row_start, int* __restrict__ eidx) {
  int b = blockIdx.x, t = threadIdx.x;
  int ebeg = scanned[b * 256];
  int eend = (b == NB - 1) ? NE : scanned[(b + 1) * 256];
  int nbase = b << 8;
  int nloc = NN - nbase; if (nloc > 256) nloc = 256;
  __shared__ int cntL[256];
  __shared__ int exclL[256];
  cntL[t] = 0;
  __syncthreads();
  for (int e = ebeg + t; e < eend; e += 256)
    atomicAdd(&cntL[part[e] >> 17], 1);
  __syncthreads();
  int c = cntL[t];
  exclL[t] = c;
  __syncthreads();
  for (int off = 1; off < 256; off <<= 1) {
    int v = (t >= off) ? exclL[t - off] : 0;
    __syncthreads();
    exclL[t] += v;
    __syncthreads();
  }
  int excl = exclL[t] - c;
  if (t < nloc) row_start[nbase + t] = ebeg + excl;
  if (b == NB - 1 && t == 0) row_start[NN] = NE;
  cntL[t] = excl;                 // reuse as cursor
  __syncthreads();
  for (int e = ebeg + t; e < eend; e += 256) {
    int v = part[e];
    int pos = atomicAdd(&cntL[v >> 17], 1);
    eidx[ebeg + pos] = v & 0x1FFFF;
  }
}

// ---------- graph boundaries: batch is sorted -> binary search ----------
__global__ __launch_bounds__(256) void bounds_kernel(
    const int* __restrict__ batch, int* __restrict__ gs) {
  int g = blockIdx.x * 256 + threadIdx.x;
  if (g > NG) return;
  if (g == NG) { gs[NG] = NN; return; }
  int lo = 0, hi = NN;
  while (lo < hi) {
    int mid = (lo + hi) >> 1;
    if (batch[mid] < g) lo = mid + 1; else hi = mid;
  }
  gs[g] = lo;
}

// ---------- fused projection v2: xl = x@W1l, xr = x@W1r + b1 ----------
// 512 threads = 8 waves; wave handles 8 nodes, lane = output feature j.
// x values are wave-uniform -> scalar loads (readfirstlane'd node index).
// Weights in LDS, j-major XOR-swizzled so lane j reads its column as
// one conflict-free 16B-aligned ds_read_b128 per k-chunk per matrix.
__global__ __launch_bounds__(512) void fused_proj_kernel(
    const float* __restrict__ x, const float* __restrict__ W1l,
    const float* __restrict__ W1r, const float* __restrict__ b1,
    float* __restrict__ xl, float* __restrict__ xr) {
  __shared__ float sWl[DIN * DH];     // 32 KB, swizzled [j][c^]
  __shared__ float sWr[DIN * DH];     // 32 KB
  for (int idx = threadIdx.x; idx < DIN * DH; idx += 512) {
    int k = idx >> 6, jj = idx & 63;            // W is [k][j]
    int c = k >> 2, r = k & 3;
    int dpos = jj * 128 + (((c ^ (jj & 31)) << 2) | r);
    sWl[dpos] = W1l[idx];
    sWr[dpos] = W1r[idx];
  }
  int wave = threadIdx.x >> 6;
  int j    = threadIdx.x & 63;
  int jm   = j & 31;
  float b1j = b1[j];
  __syncthreads();

  int node0 = __builtin_amdgcn_readfirstlane(blockIdx.x * 64 + wave * 8);
  // uniform row pointers (clamped; OOB rows masked at store)
  const float4* xrow[8];
#pragma unroll
  for (int s = 0; s < 8; ++s) {
    int n = node0 + s;
    if (n >= NN) n = NN - 1;
    xrow[s] = (const float4*)(x + (size_t)n * DIN);
  }
  float accl[8], accr[8];
#pragma unroll
  for (int s = 0; s < 8; ++s) { accl[s] = 0.f; accr[s] = 0.f; }

#pragma unroll 4
  for (int c = 0; c < 32; ++c) {
    float4 xv[8];
#pragma unroll
    for (int s = 0; s < 8; ++s) xv[s] = xrow[s][c];     // wave-uniform -> s_load
    int cp = (c ^ jm) << 2;
    float4 wl = *(const float4*)(sWl + j * 128 + cp);   // retrieves k-chunk c
    float4 wr = *(const float4*)(sWr + j * 128 + cp);
#pragma unroll
    for (int i = 0; i < 4; ++i) {
      float wli = (&wl.x)[i];
      float wri = (&wr.x)[i];
#pragma unroll
      for (int s = 0; s < 8; ++s) {
        float xs = (&xv[s].x)[i];
        accl[s] = fmaf(xs, wli, accl[s]);
        accr[s] = fmaf(xs, wri, accr[s]);
      }
    }
  }
#pragma unroll
  for (int s = 0; s < 8; ++s) {
    int node = node0 + s;
    if (node < NN) {
      xl[(size_t)node * DH + j] = accl[s];
      xr[(size_t)node * DH + j] = accr[s] + b1j;
    }
  }
}

// ---------- mean aggregation via gather: 16 lanes x float4 per node ----------
template <bool RELU_ADD>
__global__ __launch_bounds__(256) void gather_kernel(
    const float4* __restrict__ feat4, const int* __restrict__ row_start,
    const int* __restrict__ eidx, const float4* __restrict__ add4,
    float4* __restrict__ out4) {
  int t = blockIdx.x * 256 + threadIdx.x;
  int node = t >> 4;
  if (node >= NN) return;
  int fl = t & 15;
  int rs = row_start[node], re = row_start[node + 1];
  float ax = 0.f, ay = 0.f, az = 0.f, aw = 0.f;
  int k = rs;
  for (; k + 4 <= re; k += 4) {           // 4 float4 loads in flight
    int s0 = eidx[k], s1 = eidx[k + 1], s2 = eidx[k + 2], s3 = eidx[k + 3];
    float4 v0 = feat4[(size_t)s0 * 16 + fl];
    float4 v1 = feat4[(size_t)s1 * 16 + fl];
    float4 v2 = feat4[(size_t)s2 * 16 + fl];
    float4 v3 = feat4[(size_t)s3 * 16 + fl];
    ax += (v0.x + v1.x) + (v2.x + v3.x);
    ay += (v0.y + v1.y) + (v2.y + v3.y);
    az += (v0.z + v1.z) + (v2.z + v3.z);
    aw += (v0.w + v1.w) + (v2.w + v3.w);
  }
  for (; k < re; ++k) {
    float4 v = feat4[(size_t)eidx[k] * 16 + fl];
    ax += v.x; ay += v.y; az += v.z; aw += v.w;
  }
  float inv = 1.0f / fmaxf((float)(re - rs), 1.0f);
  ax *= inv; ay *= inv; az *= inv; aw *= inv;
  if (RELU_ADD) {
    float4 a = add4[(size_t)node * 16 + fl];
    ax = fmaxf(ax + a.x, 0.f); ay = fmaxf(ay + a.y, 0.f);
    az = fmaxf(az + a.z, 0.f); aw = fmaxf(aw + a.w, 0.f);
  }
  out4[(size_t)node * 16 + fl] = make_float4(ax, ay, az, aw);
}

// ---------- per-graph segment-sum of h and mean2 ----------
__global__ __launch_bounds__(256) void pool_kernel(
    const float* __restrict__ h, const float* __restrict__ m,
    const int* __restrict__ gs, float* __restrict__ hs,
    float* __restrict__ ms) {
  int g = blockIdx.x;
  int start = gs[g], end = gs[g + 1];
  int slot = threadIdx.x >> 6, j = threadIdx.x & 63;
  float sh = 0.f, sm = 0.f;
  for (int n = start + slot; n < end; n += 4) {
    sh += h[(size_t)n * DH + j];
    sm += m[(size_t)n * DH + j];
  }
  __shared__ float red[2][4][DH];
  red[0][slot][j] = sh;
  red[1][slot][j] = sm;
  __syncthreads();
  if (slot == 0) {
    sh = red[0][0][j] + red[0][1][j] + red[0][2][j] + red[0][3][j];
    sm = red[1][0][j] + red[1][1][j] + red[1][2][j] + red[1][3][j];
    hs[g * DH + j] = sh;
    ms[g * DH + j] = sm;
  }
}

// ---------- final tiny matmul ----------
__global__ __launch_bounds__(128) void final_kernel(
    const float* __restrict__ hs, const float* __restrict__ ms,
    const float* __restrict__ W2l, const float* __restrict__ W2r,
    const float* __restrict__ b2, const int* __restrict__ gs,
    float* __restrict__ out) {
  int g = blockIdx.x;
  int j = threadIdx.x;
  float n = (float)(gs[g + 1] - gs[g]);
  float acc = 0.f;
#pragma unroll 8
  for (int k = 0; k < DH; ++k)
    acc += ms[g * DH + k] * W2l[k * DOUT + j] + hs[g * DH + k] * W2r[k * DOUT + j];
  float inv = 1.0f / fmaxf(n, 1.0f);
  out[g * DOUT + j] = (acc + n * b2[j]) * inv;
}

extern "C" void kernel_launch(void* const* d_in, const int* in_sizes, int n_in,
                              void* d_out, int out_size, void* d_ws, size_t ws_size,
                              hipStream_t stream) {
  (void)in_sizes; (void)n_in; (void)out_size; (void)ws_size;
  const float* x   = (const float*)d_in[0];
  const float* W1l = (const float*)d_in[1];
  const float* W1r = (const float*)d_in[2];
  const float* b1  = (const float*)d_in[3];
  const float* W2l = (const float*)d_in[4];
  const float* W2r = (const float*)d_in[5];
  const float* b2  = (const float*)d_in[6];
  const int*   ei  = (const int*)d_in[7];
  const int*   batch = (const int*)d_in[8];
  const int* src = ei;            // edge_index[0, :]
  const int* dst = ei + NE;       // edge_index[1, :]
  float* out = (float*)d_out;

  char* ws = (char*)d_ws;
  float* bufA     = (float*)(ws);                    // 25,600,000 B (xl, then mean2)
  float* bufB     = (float*)(ws + 25600000);         // 25,600,000 B (h)
  float* bufC     = (float*)(ws + 51200000);         // 25,600,000 B (xr)
  // part/cnt/scanned overlay bufC: all dead before fused_proj writes xr
  int*  part      = (int*)(ws + 51200000);           //  6,400,000 B
  int*  cnt       = (int*)(ws + 57600000);           //    400,384 B (MSZ)
  int*  scanned   = (int*)(ws + 58000384);           //    400,384 B (MSZ)
  int*  eidx      = (int*)(ws + 76800000);           //  6,400,000 B
  int*  row_start = (int*)(ws + 83200000);           //    400,004 B
  int*   gs       = (int*)(ws + 83600128);           //      2,052 B
  float* hs       = (float*)(ws + 83604224);         //    131,072 B
  float* msum     = (float*)(ws + 83735296);         //    131,072 B
  int*  partials  = (int*)(ws + 84400128);           //      1,564 B

  const int gBlocks = (NN * 16) / 256;               // 6250
  const int pBlocks = (NN + 63) / 64;                // 1563

  // bucket-radix CSR build
  histA_kernel<<<256, 256, 0, stream>>>(dst, cnt);
  reduce_kernel<<<NB, 256, 0, stream>>>(cnt, partials);
  scanpart_kernel<<<1, 256, 0, stream>>>(partials);
  scanfinal_kernel<<<NB, 256, 0, stream>>>(cnt, partials, scanned);
  partA_kernel<<<256, 256, 0, stream>>>(src, dst, scanned, part);
  bucket_csr_kernel<<<NB, 256, 0, stream>>>(part, scanned, row_start, eidx);
  bounds_kernel<<<3, 256, 0, stream>>>(batch, gs);

  // layer 1
  fused_proj_kernel<<<pBlocks, 512, 0, stream>>>(x, W1l, W1r, b1, bufA, bufC);
  gather_kernel<true><<<gBlocks, 256, 0, stream>>>(
      (const float4*)bufA, row_start, eidx, (const float4*)bufC, (float4*)bufB);

  // layer 2 aggregation
  gather_kernel<false><<<gBlocks, 256, 0, stream>>>(
      (const float4*)bufB, row_start, eidx, nullptr, (float4*)bufA);

  // pool-then-matmul
  pool_kernel<<<NG, 256, 0, stream>>>(bufB, bufA, gs, hs, msum);
  final_kernel<<<NG, 128, 0, stream>>>(hs, msum, W2l, W2r, b2, gs, out);
}

// Round 8
// 363.408 us; speedup vs baseline: 1.0724x; 1.0724x over previous
//
#include <hip/hip_runtime.h>

#define NN   100000
#define NE   1600000
#define DIN  128
#define DH   64
#define DOUT 128
#define NG   512

#define NB   391     // dst buckets of 256 nodes: ceil(NN/256)
#define EPB  6250    // edges per partition block: NE/256
#define MSZ  (NB*256) // 100,096 — scan length

// ---------- radix pass A1: per-(block,bucket) histogram ----------
__global__ __launch_bounds__(256) void histA_kernel(
    const int* __restrict__ dst, int* __restrict__ cnt) {
  __shared__ int h[NB];
  for (int i = threadIdx.x; i < NB; i += 256) h[i] = 0;
  __syncthreads();
  int start = blockIdx.x * EPB, end = start + EPB;
  for (int e = start + threadIdx.x; e < end; e += 256)
    atomicAdd(&h[dst[e] >> 8], 1);
  __syncthreads();
  for (int b = threadIdx.x; b < NB; b += 256)
    cnt[b * 256 + blockIdx.x] = h[b];   // bucket-major layout
}

// ---------- scan pass 1: per-block sums ----------
__global__ __launch_bounds__(256) void reduce_kernel(
    const int* __restrict__ cnt, int* __restrict__ partials) {
  __shared__ int s[256];
  int i = blockIdx.x * 256 + threadIdx.x;
  s[threadIdx.x] = cnt[i];
  __syncthreads();
  for (int off = 128; off > 0; off >>= 1) {
    if (threadIdx.x < off) s[threadIdx.x] += s[threadIdx.x + off];
    __syncthreads();
  }
  if (threadIdx.x == 0) partials[blockIdx.x] = s[0];
}

// ---------- scan pass 2: exclusive scan of NB partials (1 block) ----------
__global__ __launch_bounds__(256) void scanpart_kernel(int* __restrict__ partials) {
  __shared__ int s[NB];
  for (int i = threadIdx.x; i < NB; i += 256) s[i] = partials[i];
  __syncthreads();
  if (threadIdx.x == 0) {
    int run = 0;
    for (int i = 0; i < NB; ++i) { int v = s[i]; s[i] = run; run += v; }
  }
  __syncthreads();
  for (int i = threadIdx.x; i < NB; i += 256) partials[i] = s[i];
}

// ---------- scan pass 3: per-block exclusive scan + offset ----------
__global__ __launch_bounds__(256) void scanfinal_kernel(
    const int* __restrict__ cnt, const int* __restrict__ partials,
    int* __restrict__ scanned) {
  __shared__ int s[256];
  int t = threadIdx.x;
  int i = blockIdx.x * 256 + t;
  int c = cnt[i];
  s[t] = c;
  __syncthreads();
  for (int off = 1; off < 256; off <<= 1) {
    int v = (t >= off) ? s[t - off] : 0;
    __syncthreads();
    s[t] += v;
    __syncthreads();
  }
  scanned[i] = s[t] - c + partials[blockIdx.x];
}

// ---------- radix pass A2: partition packed edges into buckets ----------
__global__ __launch_bounds__(256) void partA_kernel(
    const int* __restrict__ src, const int* __restrict__ dst,
    const int* __restrict__ scanned, int* __restrict__ part) {
  __shared__ int cur[NB];
  for (int i = threadIdx.x; i < NB; i += 256)
    cur[i] = scanned[i * 256 + blockIdx.x];
  __syncthreads();
  int start = blockIdx.x * EPB, end = start + EPB;
  for (int e = start + threadIdx.x; e < end; e += 256) {
    int d = dst[e], s = src[e];
    int pos = atomicAdd(&cur[d >> 8], 1);
    part[pos] = ((d & 255) << 17) | s;
  }
}

// ---------- radix pass B: per-bucket CSR (row_start + eidx) ----------
__global__ __launch_bounds__(256) void bucket_csr_kernel(
    const int* __restrict__ part, const int* __restrict__ scanned,
    int* __restrict__ row_start, int* __restrict__ eidx) {
  int b = blockIdx.x, t = threadIdx.x;
  int ebeg = scanned[b * 256];
  int eend = (b == NB - 1) ? NE : scanned[(b + 1) * 256];
  int nbase = b << 8;
  int nloc = NN - nbase; if (nloc > 256) nloc = 256;
  __shared__ int cntL[256];
  __shared__ int exclL[256];
  cntL[t] = 0;
  __syncthreads();
  for (int e = ebeg + t; e < eend; e += 256)
    atomicAdd(&cntL[part[e] >> 17], 1);
  __syncthreads();
  int c = cntL[t];
  exclL[t] = c;
  __syncthreads();
  for (int off = 1; off < 256; off <<= 1) {
    int v = (t >= off) ? exclL[t - off] : 0;
    __syncthreads();
    exclL[t] += v;
    __syncthreads();
  }
  int excl = exclL[t] - c;
  if (t < nloc) row_start[nbase + t] = ebeg + excl;
  if (b == NB - 1 && t == 0) row_start[NN] = NE;
  cntL[t] = excl;                 // reuse as cursor
  __syncthreads();
  for (int e = ebeg + t; e < eend; e += 256) {
    int v = part[e];
    int pos = atomicAdd(&cntL[v >> 17], 1);
    eidx[ebeg + pos] = v & 0x1FFFF;
  }
}

// ---------- graph boundaries: batch is sorted -> binary search ----------
__global__ __launch_bounds__(256) void bounds_kernel(
    const int* __restrict__ batch, int* __restrict__ gs) {
  int g = blockIdx.x * 256 + threadIdx.x;
  if (g > NG) return;
  if (g == NG) { gs[NG] = NN; return; }
  int lo = 0, hi = NN;
  while (lo < hi) {
    int mid = (lo + hi) >> 1;
    if (batch[mid] < g) lo = mid + 1; else hi = mid;
  }
  gs[g] = lo;
}

// ---------- fused projection v3: xl = x@W1l, xr = x@W1r + b1 ----------
// Round-6 structure (LDS-broadcast x, 0 conflicts) with W reads upgraded
// to conflict-free b128: W stored [c][j][r] so lane j's 4 k-values for
// chunk c are 16B-contiguous and consecutive lanes read consecutive 16B.
// Per k4 per wave: 8 LDS broadcasts (xv) + 2 b128 (w) vs 16 instr before.
__global__ __launch_bounds__(256) void fused_proj_kernel(
    const float* __restrict__ x, const float* __restrict__ W1l,
    const float* __restrict__ W1r, const float* __restrict__ b1,
    float* __restrict__ xl, float* __restrict__ xr) {
  __shared__ float sWl[DIN * DH];     // 32 KB, layout [c][j][r]
  __shared__ float sWr[DIN * DH];     // 32 KB
  __shared__ float4 xs4[32 * 32];     // 16 KB: [node_local][k4]
  for (int idx = threadIdx.x; idx < DIN * DH; idx += 256) {
    int k = idx >> 6, jj = idx & 63;  // W source is [k][j]
    int c = k >> 2, r = k & 3;
    int dpos = c * 256 + jj * 4 + r;
    sWl[dpos] = W1l[idx];
    sWr[dpos] = W1r[idx];
  }
  int wave = threadIdx.x >> 6;
  int j    = threadIdx.x & 63;
  float b1j = b1[j];
  const float4* x4 = (const float4*)x;
  int nbase = wave * 8;
  for (int tile = 0; tile < 2; ++tile) {
    int base = blockIdx.x * 64 + tile * 32;
    __syncthreads();
#pragma unroll
    for (int i = 0; i < 4; ++i) {       // stage 32 rows (coalesced float4)
      int flat = i * 256 + threadIdx.x;
      int nl = flat >> 5, k4 = flat & 31;
      int ng = base + nl;
      float4 v = make_float4(0.f, 0.f, 0.f, 0.f);
      if (ng < NN) v = x4[(size_t)ng * 32 + k4];
      xs4[nl * 32 + k4] = v;
    }
    __syncthreads();
    float accl[8], accr[8];
#pragma unroll
    for (int s = 0; s < 8; ++s) { accl[s] = 0.f; accr[s] = 0.f; }
    for (int c = 0; c < 32; ++c) {
      float4 xv[8];
#pragma unroll
      for (int s = 0; s < 8; ++s) xv[s] = xs4[(nbase + s) * 32 + c];  // broadcast
      float4 wl4 = *(const float4*)(sWl + (c << 8) + (j << 2));
      float4 wr4 = *(const float4*)(sWr + (c << 8) + (j << 2));
#pragma unroll
      for (int i = 0; i < 4; ++i) {
        float wli = (&wl4.x)[i];
        float wri = (&wr4.x)[i];
#pragma unroll
        for (int s = 0; s < 8; ++s) {
          float xsi = (&xv[s].x)[i];
          accl[s] = fmaf(xsi, wli, accl[s]);
          accr[s] = fmaf(xsi, wri, accr[s]);
        }
      }
    }
#pragma unroll
    for (int s = 0; s < 8; ++s) {
      int ng = base + nbase + s;
      if (ng < NN) {
        xl[(size_t)ng * DH + j] = accl[s];
        xr[(size_t)ng * DH + j] = accr[s] + b1j;
      }
    }
  }
}

// ---------- mean aggregation via gather: 16 lanes x float4 per node ----------
// Unrolled 8/2/1 -> up to 8 outstanding b128 gathers per lane.
template <bool RELU_ADD>
__global__ __launch_bounds__(256) void gather_kernel(
    const float4* __restrict__ feat4, const int* __restrict__ row_start,
    const int* __restrict__ eidx, const float4* __restrict__ add4,
    float4* __restrict__ out4) {
  int t = blockIdx.x * 256 + threadIdx.x;
  int node = t >> 4;
  if (node >= NN) return;
  int fl = t & 15;
  int rs = row_start[node], re = row_start[node + 1];
  float ax = 0.f, ay = 0.f, az = 0.f, aw = 0.f;
  int k = rs;
  for (; k + 8 <= re; k += 8) {           // 8 float4 loads in flight
    float4 v[8];
#pragma unroll
    for (int u = 0; u < 8; ++u) v[u] = feat4[(size_t)eidx[k + u] * 16 + fl];
#pragma unroll
    for (int u = 0; u < 8; ++u) {
      ax += v[u].x; ay += v[u].y; az += v[u].z; aw += v[u].w;
    }
  }
  for (; k + 2 <= re; k += 2) {
    float4 v0 = feat4[(size_t)eidx[k] * 16 + fl];
    float4 v1 = feat4[(size_t)eidx[k + 1] * 16 + fl];
    ax += v0.x + v1.x; ay += v0.y + v1.y;
    az += v0.z + v1.z; aw += v0.w + v1.w;
  }
  if (k < re) {
    float4 v = feat4[(size_t)eidx[k] * 16 + fl];
    ax += v.x; ay += v.y; az += v.z; aw += v.w;
  }
  float inv = 1.0f / fmaxf((float)(re - rs), 1.0f);
  ax *= inv; ay *= inv; az *= inv; aw *= inv;
  if (RELU_ADD) {
    float4 a = add4[(size_t)node * 16 + fl];
    ax = fmaxf(ax + a.x, 0.f); ay = fmaxf(ay + a.y, 0.f);
    az = fmaxf(az + a.z, 0.f); aw = fmaxf(aw + a.w, 0.f);
  }
  out4[(size_t)node * 16 + fl] = make_float4(ax, ay, az, aw);
}

// ---------- per-graph segment-sum of h and mean2 ----------
__global__ __launch_bounds__(256) void pool_kernel(
    const float* __restrict__ h, const float* __restrict__ m,
    const int* __restrict__ gs, float* __restrict__ hs,
    float* __restrict__ ms) {
  int g = blockIdx.x;
  int start = gs[g], end = gs[g + 1];
  int slot = threadIdx.x >> 6, j = threadIdx.x & 63;
  float sh = 0.f, sm = 0.f;
  for (int n = start + slot; n < end; n += 4) {
    sh += h[(size_t)n * DH + j];
    sm += m[(size_t)n * DH + j];
  }
  __shared__ float red[2][4][DH];
  red[0][slot][j] = sh;
  red[1][slot][j] = sm;
  __syncthreads();
  if (slot == 0) {
    sh = red[0][0][j] + red[0][1][j] + red[0][2][j] + red[0][3][j];
    sm = red[1][0][j] + red[1][1][j] + red[1][2][j] + red[1][3][j];
    hs[g * DH + j] = sh;
    ms[g * DH + j] = sm;
  }
}

// ---------- final tiny matmul ----------
__global__ __launch_bounds__(128) void final_kernel(
    const float* __restrict__ hs, const float* __restrict__ ms,
    const float* __restrict__ W2l, const float* __restrict__ W2r,
    const float* __restrict__ b2, const int* __restrict__ gs,
    float* __restrict__ out) {
  int g = blockIdx.x;
  int j = threadIdx.x;
  float n = (float)(gs[g + 1] - gs[g]);
  float acc = 0.f;
#pragma unroll 8
  for (int k = 0; k < DH; ++k)
    acc += ms[g * DH + k] * W2l[k * DOUT + j] + hs[g * DH + k] * W2r[k * DOUT + j];
  float inv = 1.0f / fmaxf(n, 1.0f);
  out[g * DOUT + j] = (acc + n * b2[j]) * inv;
}

extern "C" void kernel_launch(void* const* d_in, const int* in_sizes, int n_in,
                              void* d_out, int out_size, void* d_ws, size_t ws_size,
                              hipStream_t stream) {
  (void)in_sizes; (void)n_in; (void)out_size; (void)ws_size;
  const float* x   = (const float*)d_in[0];
  const float* W1l = (const float*)d_in[1];
  const float* W1r = (const float*)d_in[2];
  const float* b1  = (const float*)d_in[3];
  const float* W2l = (const float*)d_in[4];
  const float* W2r = (const float*)d_in[5];
  const float* b2  = (const float*)d_in[6];
  const int*   ei  = (const int*)d_in[7];
  const int*   batch = (const int*)d_in[8];
  const int* src = ei;            // edge_index[0, :]
  const int* dst = ei + NE;       // edge_index[1, :]
  float* out = (float*)d_out;

  char* ws = (char*)d_ws;
  float* bufA     = (float*)(ws);                    // 25,600,000 B (xl, then mean2)
  float* bufB     = (float*)(ws + 25600000);         // 25,600,000 B (h)
  float* bufC     = (float*)(ws + 51200000);         // 25,600,000 B (xr)
  // part/cnt/scanned overlay bufC: all dead before fused_proj writes xr
  int*  part      = (int*)(ws + 51200000);           //  6,400,000 B
  int*  cnt       = (int*)(ws + 57600000);           //    400,384 B (MSZ)
  int*  scanned   = (int*)(ws + 58000384);           //    400,384 B (MSZ)
  int*  eidx      = (int*)(ws + 76800000);           //  6,400,000 B
  int*  row_start = (int*)(ws + 83200000);           //    400,004 B
  int*   gs       = (int*)(ws + 83600128);           //      2,052 B
  float* hs       = (float*)(ws + 83604224);         //    131,072 B
  float* msum     = (float*)(ws + 83735296);         //    131,072 B
  int*  partials  = (int*)(ws + 84400128);           //      1,564 B

  const int gBlocks = (NN * 16) / 256;               // 6250
  const int pBlocks = (NN + 63) / 64;                // 1563

  // bucket-radix CSR build
  histA_kernel<<<256, 256, 0, stream>>>(dst, cnt);
  reduce_kernel<<<NB, 256, 0, stream>>>(cnt, partials);
  scanpart_kernel<<<1, 256, 0, stream>>>(partials);
  scanfinal_kernel<<<NB, 256, 0, stream>>>(cnt, partials, scanned);
  partA_kernel<<<256, 256, 0, stream>>>(src, dst, scanned, part);
  bucket_csr_kernel<<<NB, 256, 0, stream>>>(part, scanned, row_start, eidx);
  bounds_kernel<<<3, 256, 0, stream>>>(batch, gs);

  // layer 1
  fused_proj_kernel<<<pBlocks, 256, 0, stream>>>(x, W1l, W1r, b1, bufA, bufC);
  gather_kernel<true><<<gBlocks, 256, 0, stream>>>(
      (const float4*)bufA, row_start, eidx, (const float4*)bufC, (float4*)bufB);

  // layer 2 aggregation
  gather_kernel<false><<<gBlocks, 256, 0, stream>>>(
      (const float4*)bufB, row_start, eidx, nullptr, (float4*)bufA);

  // pool-then-matmul
  pool_kernel<<<NG, 256, 0, stream>>>(bufB, bufA, gs, hs, msum);
  final_kernel<<<NG, 128, 0, stream>>>(hs, msum, W2l, W2r, b2, gs, out);
}